// Round 10
// baseline (288.871 us; speedup 1.0000x reference)
//
#include <hip/hip_runtime.h>

#define HW 3136
#define NB 32
#define NC 128

// Packed fp32 FMA helpers (VOP3P v_pk_fma_f32). src0 is a float2 pair holding
// two coefficients; op_sel/op_sel_hi broadcast the LO (b0) or HI (b1) word of
// src0 to both halves. pkn* fold the negation of src0 via neg_lo/neg_hi.
// d = (+/-)bcast(c) * v + a   elementwise on the pair.
static __device__ __forceinline__ float2 pka0(float2 c, float2 v, float2 a) {
  float2 d;
  asm("v_pk_fma_f32 %0, %1, %2, %3 op_sel:[0,0,0] op_sel_hi:[0,1,1]"
      : "=v"(d) : "v"(c), "v"(v), "v"(a));
  return d;
}
static __device__ __forceinline__ float2 pka1(float2 c, float2 v, float2 a) {
  float2 d;
  asm("v_pk_fma_f32 %0, %1, %2, %3 op_sel:[1,0,0] op_sel_hi:[1,1,1]"
      : "=v"(d) : "v"(c), "v"(v), "v"(a));
  return d;
}
static __device__ __forceinline__ float2 pkn0(float2 c, float2 v, float2 a) {
  float2 d;
  asm("v_pk_fma_f32 %0, %1, %2, %3 op_sel:[0,0,0] op_sel_hi:[0,1,1] neg_lo:[1,0,0] neg_hi:[1,0,0]"
      : "=v"(d) : "v"(c), "v"(v), "v"(a));
  return d;
}
static __device__ __forceinline__ float2 pkn1(float2 c, float2 v, float2 a) {
  float2 d;
  asm("v_pk_fma_f32 %0, %1, %2, %3 op_sel:[1,0,0] op_sel_hi:[1,1,1] neg_lo:[1,0,0] neg_hi:[1,0,0]"
      : "=v"(d) : "v"(c), "v"(v), "v"(a));
  return d;
}

// 512 threads: thread owns 8 rows x 4 cols, stored as float2 pairs
// aP[r][0] = cols c0,c0+1 ; aP[r][1] = cols c0+2,c0+3.
__global__ __launch_bounds__(512, 4)
void mvg_kernel(const float* __restrict__ emb, float* __restrict__ out) {
  // XCD-bijective swizzle (3136 = 8*392): contiguous pos chunk per XCD.
  const int bid = blockIdx.x;
  const int pos = (bid & 7) * 392 + (bid >> 3);
  const int t = threadIdx.x;
  const int rm = t >> 5;
  const int cm = t & 31;
  const int i0 = rm << 3;
  const int c0 = cm << 2;

  __shared__ float Xs[NB * NC];                    // dense 16 KB slice
  __shared__ __align__(16) float Hb[2][2][132];    // h rows, [parity][j][.]
  __shared__ __align__(16) float Gb[2][2][132];    // g rows = h/d
  __shared__ float ms[NC];

  // ---- gather the (B, C) slice ----
  #pragma unroll
  for (int m = 0; m < 8; ++m) {
    const int idx = t + 512 * m;
    const int b = idx >> 7;
    const int c = idx & (NC - 1);
    Xs[idx] = emb[(size_t)b * (size_t)(NC * HW) + (size_t)c * HW + pos];
  }
  __syncthreads();

  // ---- mean over batch, write mean output ----
  if (t < NC) {
    float s = 0.f;
    #pragma unroll
    for (int b = 0; b < NB; ++b) s += Xs[b * NC + t];
    const float m = s * (1.0f / NB);
    ms[t] = m;
    out[(size_t)t * HW + pos] = m;
  }
  __syncthreads();

  // ---- center ----
  #pragma unroll
  for (int m = 0; m < 8; ++m) {
    const int idx = t + 512 * m;
    Xs[idx] -= ms[idx & (NC - 1)];
  }
  __syncthreads();

  float2 aP[8][2];
  #pragma unroll
  for (int r = 0; r < 8; ++r) {
    aP[r][0] = make_float2(0.f, 0.f);
    aP[r][1] = make_float2(0.f, 0.f);
  }

  // ---- covariance accumulate (packed: 16 pk-FMA per batch row) ----
  for (int b = 0; b < NB; ++b) {
    const float* xr = &Xs[b * NC];
    const float4 rv  = *(const float4*)&xr[c0];
    const float4 cv0 = *(const float4*)&xr[i0];
    const float4 cv1 = *(const float4*)&xr[i0 + 4];
    const float2 rL = make_float2(rv.x, rv.y), rH = make_float2(rv.z, rv.w);
    const float2 c01 = make_float2(cv0.x, cv0.y), c23 = make_float2(cv0.z, cv0.w);
    const float2 c45 = make_float2(cv1.x, cv1.y), c67 = make_float2(cv1.z, cv1.w);
    aP[0][0] = pka0(c01, rL, aP[0][0]); aP[0][1] = pka0(c01, rH, aP[0][1]);
    aP[1][0] = pka1(c01, rL, aP[1][0]); aP[1][1] = pka1(c01, rH, aP[1][1]);
    aP[2][0] = pka0(c23, rL, aP[2][0]); aP[2][1] = pka0(c23, rH, aP[2][1]);
    aP[3][0] = pka1(c23, rL, aP[3][0]); aP[3][1] = pka1(c23, rH, aP[3][1]);
    aP[4][0] = pka0(c45, rL, aP[4][0]); aP[4][1] = pka0(c45, rH, aP[4][1]);
    aP[5][0] = pka1(c45, rL, aP[5][0]); aP[5][1] = pka1(c45, rH, aP[5][1]);
    aP[6][0] = pka0(c67, rL, aP[6][0]); aP[6][1] = pka0(c67, rH, aP[6][1]);
    aP[7][0] = pka1(c67, rL, aP[7][0]); aP[7][1] = pka1(c67, rH, aP[7][1]);
  }

  // ---- scale 1/(B-1), + (REG_DIAG+REG_EPS) I ----
  {
    const float s31 = 1.0f / (float)(NB - 1);
    const float RD = 0.01f + 1e-5f;
    #pragma unroll
    for (int r = 0; r < 8; ++r) {
      const int gr = i0 + r;
      aP[r][0].x = aP[r][0].x * s31 + ((gr == c0 + 0) ? RD : 0.f);
      aP[r][0].y = aP[r][0].y * s31 + ((gr == c0 + 1) ? RD : 0.f);
      aP[r][1].x = aP[r][1].x * s31 + ((gr == c0 + 2) ? RD : 0.f);
      aP[r][1].y = aP[r][1].y * s31 + ((gr == c0 + 3) ? RD : 0.f);
    }
  }

  // PAIR(Q,J,PB,CK,CK1,JH): pivots k=8Q+2J, k+1 (col k at thread cmd=2Q+JH,
  // float4 component CK; col k+1 component CK1). Owner group (rm==Q) builds
  // h_k, g_k, h_k+1, g_k+1 exactly as R9 (h-encoding: -1 at the pivot slot),
  // publishes pre-barrier; post-barrier everyone applies the packed rank-2
  // update a[r] -= g_k[i0+r]*h_k + g_k+1[i0+r]*h_s with op_sel broadcasts.
  #define PAIR(Q, J, PB, CK, CK1, JH) {                                     \
    if (rm == (Q)) {                                                        \
      const int cmd = 2 * (Q) + (JH);                                       \
      float4 hk = make_float4(aP[2*(J)][0].x, aP[2*(J)][0].y,               \
                              aP[2*(J)][1].x, aP[2*(J)][1].y);              \
      if (cm == cmd) hk.CK -= 1.0f;                                         \
      const float d0 = __shfl(hk.CK, cmd, 32) + 1.0f;                       \
      const float rd0 = __builtin_amdgcn_rcpf(d0);                          \
      float4 gk;                                                            \
      gk.x = hk.x * rd0; gk.y = hk.y * rd0;                                 \
      gk.z = hk.z * rd0; gk.w = hk.w * rd0;                                 \
      const float ck1 = __shfl(gk.CK1, cmd, 32);                            \
      float4 hs;                                                            \
      hs.x = fmaf(-ck1, hk.x, aP[2*(J)+1][0].x);                            \
      hs.y = fmaf(-ck1, hk.y, aP[2*(J)+1][0].y);                            \
      hs.z = fmaf(-ck1, hk.z, aP[2*(J)+1][1].x);                            \
      hs.w = fmaf(-ck1, hk.w, aP[2*(J)+1][1].y);                            \
      if (cm == cmd) hs.CK1 -= 1.0f;                                        \
      const float d1 = __shfl(hs.CK1, cmd, 32) + 1.0f;                      \
      const float rd1 = __builtin_amdgcn_rcpf(d1);                          \
      float4 gs;                                                            \
      gs.x = hs.x * rd1; gs.y = hs.y * rd1;                                 \
      gs.z = hs.z * rd1; gs.w = hs.w * rd1;                                 \
      *(float4*)&Hb[PB][0][c0] = hk;                                        \
      *(float4*)&Hb[PB][1][c0] = hs;                                        \
      *(float4*)&Gb[PB][0][c0] = gk;                                        \
      *(float4*)&Gb[PB][1][c0] = gs;                                        \
    }                                                                       \
    __syncthreads();                                                        \
    {                                                                       \
      const float4 hr4 = *(const float4*)&Hb[PB][0][c0];                    \
      const float4 hs4 = *(const float4*)&Hb[PB][1][c0];                    \
      const float4 ga0 = *(const float4*)&Gb[PB][0][i0];                    \
      const float4 ga1 = *(const float4*)&Gb[PB][0][i0 + 4];                \
      const float4 gb0 = *(const float4*)&Gb[PB][1][i0];                    \
      const float4 gb1 = *(const float4*)&Gb[PB][1][i0 + 4];                \
      const float2 hrL = make_float2(hr4.x, hr4.y);                         \
      const float2 hrH = make_float2(hr4.z, hr4.w);                         \
      const float2 hsL = make_float2(hs4.x, hs4.y);                         \
      const float2 hsH = make_float2(hs4.z, hs4.w);                         \
      const float2 A01 = make_float2(ga0.x, ga0.y);                         \
      const float2 A23 = make_float2(ga0.z, ga0.w);                         \
      const float2 A45 = make_float2(ga1.x, ga1.y);                         \
      const float2 A67 = make_float2(ga1.z, ga1.w);                         \
      const float2 B01 = make_float2(gb0.x, gb0.y);                         \
      const float2 B23 = make_float2(gb0.z, gb0.w);                         \
      const float2 B45 = make_float2(gb1.x, gb1.y);                         \
      const float2 B67 = make_float2(gb1.z, gb1.w);                         \
      aP[0][0] = pkn0(A01, hrL, pkn0(B01, hsL, aP[0][0]));                  \
      aP[0][1] = pkn0(A01, hrH, pkn0(B01, hsH, aP[0][1]));                  \
      aP[1][0] = pkn1(A01, hrL, pkn1(B01, hsL, aP[1][0]));                  \
      aP[1][1] = pkn1(A01, hrH, pkn1(B01, hsH, aP[1][1]));                  \
      aP[2][0] = pkn0(A23, hrL, pkn0(B23, hsL, aP[2][0]));                  \
      aP[2][1] = pkn0(A23, hrH, pkn0(B23, hsH, aP[2][1]));                  \
      aP[3][0] = pkn1(A23, hrL, pkn1(B23, hsL, aP[3][0]));                  \
      aP[3][1] = pkn1(A23, hrH, pkn1(B23, hsH, aP[3][1]));                  \
      aP[4][0] = pkn0(A45, hrL, pkn0(B45, hsL, aP[4][0]));                  \
      aP[4][1] = pkn0(A45, hrH, pkn0(B45, hsH, aP[4][1]));                  \
      aP[5][0] = pkn1(A45, hrL, pkn1(B45, hsL, aP[5][0]));                  \
      aP[5][1] = pkn1(A45, hrH, pkn1(B45, hsH, aP[5][1]));                  \
      aP[6][0] = pkn0(A67, hrL, pkn0(B67, hsL, aP[6][0]));                  \
      aP[6][1] = pkn0(A67, hrH, pkn0(B67, hsH, aP[6][1]));                  \
      aP[7][0] = pkn1(A67, hrL, pkn1(B67, hsL, aP[7][0]));                  \
      aP[7][1] = pkn1(A67, hrH, pkn1(B67, hsH, aP[7][1]));                  \
    }                                                                       \
  }

  // ---- 64 rank-2 steps: 16 iterations x 4 static pairs ----
  #pragma unroll 1
  for (int q = 0; q < 16; ++q) {
    PAIR(q, 0, 0, x, y, 0)    // k = 8q+0
    PAIR(q, 1, 1, z, w, 0)    // k = 8q+2
    PAIR(q, 2, 0, x, y, 1)    // k = 8q+4
    PAIR(q, 3, 1, z, w, 1)    // k = 8q+6
  }

  // ---- store: inv = -a, diag = 2 - a (undo the +2 encoding artifact) ----
  float* o = out + (size_t)NC * HW + (size_t)pos * (NC * NC);
  #pragma unroll
  for (int r = 0; r < 8; ++r) {
    const int gr = i0 + r;
    float4 w;
    w.x = (gr == c0 + 0) ? (2.0f - aP[r][0].x) : (-aP[r][0].x);
    w.y = (gr == c0 + 1) ? (2.0f - aP[r][0].y) : (-aP[r][0].y);
    w.z = (gr == c0 + 2) ? (2.0f - aP[r][1].x) : (-aP[r][1].x);
    w.w = (gr == c0 + 3) ? (2.0f - aP[r][1].y) : (-aP[r][1].y);
    *(float4*)&o[(size_t)gr * NC + c0] = w;
  }
}

extern "C" void kernel_launch(void* const* d_in, const int* in_sizes, int n_in,
                              void* d_out, int out_size, void* d_ws, size_t ws_size,
                              hipStream_t stream) {
  const float* emb = (const float*)d_in[0];
  float* out = (float*)d_out;
  mvg_kernel<<<HW, 512, 0, stream>>>(emb, out);
}